// Round 2
// baseline (77.655 us; speedup 1.0000x reference)
//
#include <hip/hip_runtime.h>

// SineGen — accurate-phase formulation.
// Reference comparison is vs a high-precision numpy recomputation (threshold =
// 2% of ref absmax = 3.61e-3). Sequential-f32 phase replication drifts ~0.1 rev
// from the exact sum and FAILS (round 1, absmax 0.20). So: compute phase in f64.
//
// phase(b,t,u,h) = (S(b,t) + (u+1)*f0(b,t)) * (h+1)/44100 + ri(b,h)
//   S(b,t) = sum_{t'<t} 256*f0(b,t')      (16 f64 scans of 1000 elements)
// out = voiced ? sin(2*pi*phase)*0.1 + 0.003*noise : (0.1/3)*noise

constexpr int B   = 16;
constexpr int T   = 1000;
constexpr int UPP = 256;
constexpr int H   = 9;          // HARMONIC_NUM + 1

__global__ __launch_bounds__(1024)
void sinegen_scan_kernel(const float* __restrict__ f0,
                         double* __restrict__ S /* [B][T] exclusive prefix */) {
    const int b = blockIdx.x;
    const int t = threadIdx.x;
    __shared__ double lds[1024];

    double d = 0.0;
    if (t < T) d = 256.0 * (double)f0[b * T + t];
    lds[t] = d;
    __syncthreads();

    // Hillis–Steele inclusive scan over 1024 slots (read, sync, write, sync)
    for (int off = 1; off < 1024; off <<= 1) {
        double add = (t >= off) ? lds[t - off] : 0.0;
        __syncthreads();
        lds[t] += add;
        __syncthreads();
    }
    if (t < T) S[b * T + t] = (t > 0) ? lds[t - 1] : 0.0;
}

__global__ __launch_bounds__(256, 4)
void sinegen_emit_kernel(const float* __restrict__ f0,
                         const float* __restrict__ rand_ini,
                         const float* __restrict__ noise,
                         const double* __restrict__ S,
                         float* __restrict__ out) {
    const int blk = blockIdx.x;          // b*T + t
    const int b   = blk / T;
    const int tid = threadIdx.x;

    __shared__ double ri[H];
    __shared__ double kh[H];
    if (tid < H) {
        ri[tid] = (double)rand_ini[b * H + tid];
        kh[tid] = (double)(tid + 1) / 44100.0;
    }
    __syncthreads();

    const float  f0v    = f0[blk];
    const double Sx     = S[blk];
    const bool   voiced = (f0v > 0.0f);
    const int    base   = blk * (UPP * H);   // 2304 consecutive outputs/frame
    const double TWO_PI = 6.283185307179586;

    if (voiced) {
        const double f0d = (double)f0v;
        #pragma unroll
        for (int k = 0; k < (UPP * H) / 256; ++k) {
            const int idx = tid + k * 256;           // 0..2303, coalesced
            const int h   = idx % H;
            const int u   = idx / H;                 // in-frame sample, 0-based
            const double p  = (Sx + (double)(u + 1) * f0d) * kh[h] + ri[h];
            const double fr = p - floor(p);          // p >= 0 here
            const float  x  = (float)(TWO_PI * fr);  // [0, 2*pi)
            const float  o  = sinf(x) * 0.1f + 0.003f * noise[base + idx];
            out[base + idx] = o;
        }
    } else {
        const float amp = (float)(0.1 / 3.0);
        #pragma unroll
        for (int k = 0; k < (UPP * H) / 256; ++k) {
            const int idx = tid + k * 256;
            out[base + idx] = amp * noise[base + idx];
        }
    }
}

extern "C" void kernel_launch(void* const* d_in, const int* in_sizes, int n_in,
                              void* d_out, int out_size, void* d_ws, size_t ws_size,
                              hipStream_t stream) {
    const float* f0       = (const float*)d_in[0];   // [B][T]
    const float* rand_ini = (const float*)d_in[1];   // [B][H]
    const float* noise    = (const float*)d_in[2];   // [B][T*UPP][H]
    float*       out      = (float*)d_out;           // [B][T*UPP][H]
    double*      S        = (double*)d_ws;           // [B][T] = 128 KB

    sinegen_scan_kernel<<<B, 1024, 0, stream>>>(f0, S);
    sinegen_emit_kernel<<<B * T, 256, 0, stream>>>(f0, rand_ini, noise, S, out);
}

// Round 3
// 62.844 us; speedup vs baseline: 1.2357x; 1.2357x over previous
//
#include <hip/hip_runtime.h>

// SineGen — accurate-phase formulation, round 3: strip per-element f64 + sinf.
//
// phase(b,t,u,h) = (S + (u+1)*f0) * kh + ri,  kh=(h+1)/44100,
//   S(b,t) = sum_{t'<t} 256*f0(b,t')   (16 f64 scans of 1000)
// Per frame (f64, lanes 0..8):  Mh = frac(S*kh + ri),  Dh = frac(f0*kh)
// Per element (all f32):        fr = fract(fmaf(u+1, Dh, Mh));  s = v_sin(fr)
//   v_sin_f32 takes REVOLUTIONS: D = sin(2*pi*S0). Max f32 error here
//   ~ulp(257)/2 in the fma = 1.5e-5 rev -> 1e-5 in output; threshold 3.6e-3.

constexpr int B   = 16;
constexpr int T   = 1000;
constexpr int UPP = 256;
constexpr int H   = 9;          // HARMONIC_NUM + 1

__global__ __launch_bounds__(1024)
void sinegen_scan_kernel(const float* __restrict__ f0,
                         double* __restrict__ S /* [B][T] exclusive prefix */) {
    const int b = blockIdx.x;
    const int t = threadIdx.x;
    __shared__ double lds[1024];

    double d = 0.0;
    if (t < T) d = 256.0 * (double)f0[b * T + t];
    lds[t] = d;
    __syncthreads();

    for (int off = 1; off < 1024; off <<= 1) {
        double add = (t >= off) ? lds[t - off] : 0.0;
        __syncthreads();
        lds[t] += add;
        __syncthreads();
    }
    if (t < T) S[b * T + t] = (t > 0) ? lds[t - 1] : 0.0;
}

__global__ __launch_bounds__(576, 2)
void sinegen_emit_kernel(const float* __restrict__ f0,
                         const float* __restrict__ rand_ini,
                         const float* __restrict__ noise,
                         const double* __restrict__ S,
                         float* __restrict__ out) {
    const int blk = blockIdx.x;          // b*T + t
    const int b   = blk / T;
    const int tid = threadIdx.x;         // 0..575, one float4 each

    __shared__ float Mh[H];              // frac(S*kh + ri)  per harmonic
    __shared__ float Dh[H];              // frac(f0*kh)      per harmonic

    const float f0v = f0[blk];

    if (tid < H) {
        const double kh = (double)(tid + 1) * (1.0 / 44100.0);
        double md = S[blk] * kh + (double)rand_ini[b * H + tid];
        Mh[tid] = (float)(md - floor(md));
        double dd = (double)f0v * kh;
        Dh[tid] = (float)(dd - floor(dd));
    }
    __syncthreads();

    const int base = blk * (UPP * H) + tid * 4;   // coalesced float4
    const float4 nz = *(const float4*)(noise + base);
    float4 o;

    if (f0v > 0.0f) {
        #pragma unroll
        for (int j = 0; j < 4; ++j) {
            const int   e  = tid * 4 + j;         // 0..2303
            const int   u  = e / 9;               // const-div -> magic mul
            const int   h  = e - u * 9;
            const float p  = fmaf((float)(u + 1), Dh[h], Mh[h]);
            const float fr = p - floorf(p);       // revolutions in [0,1)
            float s;
            asm("v_sin_f32 %0, %1" : "=v"(s) : "v"(fr));  // sin(2*pi*fr)
            const float n = (&nz.x)[j];
            (&o.x)[j] = fmaf(0.003f, n, 0.1f * s);
        }
    } else {
        const float amp = (float)(0.1 / 3.0);
        #pragma unroll
        for (int j = 0; j < 4; ++j) (&o.x)[j] = amp * (&nz.x)[j];
    }

    *(float4*)(out + base) = o;
}

extern "C" void kernel_launch(void* const* d_in, const int* in_sizes, int n_in,
                              void* d_out, int out_size, void* d_ws, size_t ws_size,
                              hipStream_t stream) {
    const float* f0       = (const float*)d_in[0];   // [B][T]
    const float* rand_ini = (const float*)d_in[1];   // [B][H]
    const float* noise    = (const float*)d_in[2];   // [B][T*UPP][H]
    float*       out      = (float*)d_out;           // [B][T*UPP][H]
    double*      Sws      = (double*)d_ws;           // [B][T] = 128 KB

    sinegen_scan_kernel<<<B, 1024, 0, stream>>>(f0, Sws);
    sinegen_emit_kernel<<<B * T, 576, 0, stream>>>(f0, rand_ini, noise, Sws, out);
}

// Round 4
// 52.906 us; speedup vs baseline: 1.4678x; 1.1878x over previous
//
#include <hip/hip_runtime.h>

// SineGen — accurate-phase formulation, round 4: ILP + L3-friendly stores.
//
// phase(b,t,u,h) = (S + (u+1)*f0) * kh + ri,  kh=(h+1)/44100,
//   S(b,t) = sum_{t'<t} 256*f0(b,t')   (16 f64 scans of 1000)
// Per frame (f64, setup lanes):  M = frac(S*kh + ri),  D = frac(f0*kh)
// Per element (f32):             fr = fract(fmaf(u+1, D, M));  s = v_sin(fr)
// Branchless: out = An*noise + As*sin,  (As,An) = voiced ? (0.1, 0.003)
//                                                        : (0,   0.1/3)
// Emit: 4 frames/block, 576 thr, 4x float4/thread (ILP=4), nontemporal stores
// (out has zero reuse; avoid evicting the noise stream from L3 across replays).

constexpr int B   = 16;
constexpr int T   = 1000;
constexpr int UPP = 256;
constexpr int H   = 9;          // HARMONIC_NUM + 1
constexpr int FPB = 4;          // frames per block (250 | T, no batch crossing)
constexpr int FRAME = UPP * H;  // 2304 floats per frame

typedef float f32x4 __attribute__((ext_vector_type(4)));

__global__ __launch_bounds__(1024)
void sinegen_scan_kernel(const float* __restrict__ f0,
                         double* __restrict__ S /* [B][T] exclusive prefix */) {
    const int b = blockIdx.x;
    const int t = threadIdx.x;
    __shared__ double lds[1024];

    double d = 0.0;
    if (t < T) d = 256.0 * (double)f0[b * T + t];
    lds[t] = d;
    __syncthreads();

    for (int off = 1; off < 1024; off <<= 1) {
        double add = (t >= off) ? lds[t - off] : 0.0;
        __syncthreads();
        lds[t] += add;
        __syncthreads();
    }
    if (t < T) S[b * T + t] = (t > 0) ? lds[t - 1] : 0.0;
}

__global__ __launch_bounds__(576)
void sinegen_emit_kernel(const float* __restrict__ f0,
                         const float* __restrict__ rand_ini,
                         const float* __restrict__ noise,
                         const double* __restrict__ S,
                         float* __restrict__ out) {
    const int blk = blockIdx.x;          // 0 .. B*T/FPB-1
    const int tid = threadIdx.x;         // 0..575

    __shared__ float2 MD[FPB][H];        // {D, M} per (frame, harmonic)
    __shared__ float2 AMP[FPB];          // {As, An} per frame

    if (tid < FPB * H) {
        const int q  = tid / H;
        const int h  = tid - q * H;
        const int fg = blk * FPB + q;    // global frame index = b*T + t
        const int b  = fg / T;
        const float  f0v = f0[fg];
        const double kh  = (double)(h + 1) * (1.0 / 44100.0);
        const double md  = S[fg] * kh + (double)rand_ini[b * H + h];
        const double dd  = (double)f0v * kh;
        MD[q][h] = make_float2((float)(dd - floor(dd)),
                               (float)(md - floor(md)));
        if (h == 0)
            AMP[q] = (f0v > 0.0f) ? make_float2(0.1f, 0.003f)
                                  : make_float2(0.0f, (float)(0.1 / 3.0));
    }
    __syncthreads();

    const int base = blk * (FPB * FRAME) + tid * 4;

    // Issue all 4 frame-strided float4 loads first (ILP=4), fully coalesced.
    f32x4 nz[FPB];
    #pragma unroll
    for (int q = 0; q < FPB; ++q)
        nz[q] = *(const f32x4*)(noise + base + q * FRAME);

    f32x4 o[FPB];
    #pragma unroll
    for (int j = 0; j < 4; ++j) {
        const int   e  = tid * 4 + j;    // 0..2303 (same split for all frames)
        const int   u  = e / 9;          // const-div -> magic mul
        const int   h  = e - u * 9;
        const float uf = (float)(u + 1);
        #pragma unroll
        for (int q = 0; q < FPB; ++q) {
            const float2 md = MD[q][h];                    // one ds_read_b64
            const float  p  = fmaf(uf, md.x, md.y);
            const float  fr = __builtin_amdgcn_fractf(p);  // v_fract_f32
            float s;
            asm("v_sin_f32 %0, %1" : "=v"(s) : "v"(fr));   // sin(2*pi*fr)
            o[q][j] = fmaf(AMP[q].y, nz[q][j], AMP[q].x * s);
        }
    }

    #pragma unroll
    for (int q = 0; q < FPB; ++q)
        __builtin_nontemporal_store(o[q], (f32x4*)(out + base + q * FRAME));
}

extern "C" void kernel_launch(void* const* d_in, const int* in_sizes, int n_in,
                              void* d_out, int out_size, void* d_ws, size_t ws_size,
                              hipStream_t stream) {
    const float* f0       = (const float*)d_in[0];   // [B][T]
    const float* rand_ini = (const float*)d_in[1];   // [B][H]
    const float* noise    = (const float*)d_in[2];   // [B][T*UPP][H]
    float*       out      = (float*)d_out;           // [B][T*UPP][H]
    double*      Sws      = (double*)d_ws;           // [B][T] = 128 KB

    sinegen_scan_kernel<<<B, 1024, 0, stream>>>(f0, Sws);
    sinegen_emit_kernel<<<(B * T) / FPB, 576, 0, stream>>>(f0, rand_ini, noise,
                                                           Sws, out);
}